// Round 2
// baseline (275.362 us; speedup 1.0000x reference)
//
#include <hip/hip_runtime.h>
#include <math.h>

// Problem constants (fixed by the reference)
#define HW 262144            // 512*512
#define TOTAL 12582912       // 48 planes * HW
#define TS 32                // output tile size
#define BUFSZ 3072           // per-level LDS region capacity (max needed ~2304)

#define CR 0.8910065241883679f   // cos(27 deg)
#define SR 0.45399049973954675f  // sin(27 deg)

__device__ __forceinline__ int iclamp511(int v) { return min(max(v, 0), 511); }

// Generic bilinear resample of one LDS region into another.
// Pixel-space affine: fx = A*px + B*py + C ; fy = D*px + E*py + F.
// AXIS=true hoists the y math (B==0, D==0).
template <bool AXIS>
__device__ __forceinline__ void eval_lds(int tid,
    float A, float B, float C, float D, float E, float F,
    const float* __restrict__ src, int sx0, int sy0, int sw,
    float* __restrict__ dst, int dx0, int dy0, int dw, int dh)
{
    for (int ly = tid >> 5; ly < dh; ly += 8) {
        float py = (float)(dy0 + ly);
        float fyb = E * py + F;
        float fxb = B * py + C;
        float wyA0 = 0.f, wyA1 = 0.f;
        int rA0 = 0, rA1 = 0;
        bool vyA0 = false, vyA1 = false;
        if (AXIS) {
            float fy = fyb;
            float yf = floorf(fy);
            wyA1 = fy - yf; wyA0 = 1.f - wyA1;
            int y0 = (int)yf, y1 = y0 + 1;
            vyA0 = (unsigned)y0 < 512u; vyA1 = (unsigned)y1 < 512u;
            rA0 = (iclamp511(y0) - sy0) * sw;
            rA1 = (iclamp511(y1) - sy0) * sw;
        }
        for (int lx = tid & 31; lx < dw; lx += 32) {
            float px = (float)(dx0 + lx);
            float fx = A * px + fxb;
            float xf = floorf(fx);
            float wx1 = fx - xf, wx0 = 1.f - wx1;
            int x0 = (int)xf, x1 = x0 + 1;
            bool vx0 = (unsigned)x0 < 512u, vx1 = (unsigned)x1 < 512u;
            int xc0 = iclamp511(x0) - sx0, xc1 = iclamp511(x1) - sx0;

            float wy0, wy1; int r0, r1; bool vy0, vy1;
            if (AXIS) {
                wy0 = wyA0; wy1 = wyA1; r0 = rA0; r1 = rA1; vy0 = vyA0; vy1 = vyA1;
            } else {
                float fy = D * px + fyb;
                float yf = floorf(fy);
                wy1 = fy - yf; wy0 = 1.f - wy1;
                int y0 = (int)yf, y1 = y0 + 1;
                vy0 = (unsigned)y0 < 512u; vy1 = (unsigned)y1 < 512u;
                r0 = (iclamp511(y0) - sy0) * sw;
                r1 = (iclamp511(y1) - sy0) * sw;
            }
            float v00 = src[r0 + xc0]; if (!(vx0 && vy0)) v00 = 0.f;
            float v01 = src[r0 + xc1]; if (!(vx1 && vy0)) v01 = 0.f;
            float v10 = src[r1 + xc0]; if (!(vx0 && vy1)) v10 = 0.f;
            float v11 = src[r1 + xc1]; if (!(vx1 && vy1)) v11 = 0.f;
            dst[ly * dw + lx] = v00 * (wy0 * wx0) + v01 * (wy0 * wx1)
                              + v10 * (wy1 * wx0) + v11 * (wy1 * wx1);
        }
    }
}

// All 6 img stages fused per 32x32 output tile. Stage1 (mirror) is an exact
// integer flip folded into stage2's global gather. Stages 2..5 produce
// intermediate regions in ping-pong LDS; stage 6 writes the output tile.
__global__ __launch_bounds__(256) void fused_img(const float* __restrict__ in,
                                                 float* __restrict__ out)
{
    __shared__ float bufA[BUFSZ];
    __shared__ float bufB[BUFSZ];
    int tid = threadIdx.x;
    int b = blockIdx.x;
    int plane = b >> 8;         // 256 tiles per plane
    int tile = b & 255;
    int tx0 = (tile & 15) * TS, ty0 = (tile >> 4) * TS;
    const float* gin = in + plane * HW;
    float* gout = out + plane * HW;

    // pixel-space coeffs, idx 1..4 = stages 3..6 (scale, zoom, rotate, shear)
    // (idx 0 = stage2/translate, unused in the region loop)
    const float KA[5] = {1.0f, 1.1f, 0.9f, CR, 1.0f};
    const float KB[5] = {0.0f, 0.0f, 0.0f, -SR, 0.05f};
    const float KC[5] = {15.36f, 255.5f - 255.5f * 1.1f, 255.5f - 255.5f * 0.9f,
                         255.5f - 255.5f * (CR - SR), 255.5f - 255.5f * 1.05f};
    const float KD[5] = {0.0f, 0.0f, 0.0f, SR, -0.03f};
    const float KE[5] = {1.0f, 0.95f, 0.9f, CR, 1.0f};
    const float KF[5] = {-10.24f, 255.5f - 255.5f * 0.95f, 255.5f - 255.5f * 0.9f,
                         255.5f - 255.5f * (SR + CR), 255.5f - 255.5f * 0.97f};

    // R[i] = needed region of stage-i output (inclusive coords). R[6] = tile.
    int Rx0[7], Rx1[7], Ry0[7], Ry1[7];
    Rx0[6] = tx0; Rx1[6] = tx0 + TS - 1; Ry0[6] = ty0; Ry1[6] = ty0 + TS - 1;
    bool empty = false;
    #pragma unroll
    for (int i = 6; i >= 3; --i) {
        int c = i - 2;
        float xa = (float)Rx0[i], xb = (float)Rx1[i];
        float ya = (float)Ry0[i], yb = (float)Ry1[i];
        // monotone linear -> separable min/max over corners
        float ax1v = KA[c] * xa, ax2v = KA[c] * xb;
        float bx1v = KB[c] * ya, bx2v = KB[c] * yb;
        float mnx = fminf(ax1v, ax2v) + fminf(bx1v, bx2v) + KC[c];
        float mxx = fmaxf(ax1v, ax2v) + fmaxf(bx1v, bx2v) + KC[c];
        float dy1v = KD[c] * xa, dy2v = KD[c] * xb;
        float ey1v = KE[c] * ya, ey2v = KE[c] * yb;
        float mny = fminf(dy1v, dy2v) + fminf(ey1v, ey2v) + KF[c];
        float mxy = fmaxf(dy1v, dy2v) + fmaxf(ey1v, ey2v) + KF[c];
        int x0 = max((int)floorf(mnx), 0), x1 = min((int)floorf(mxx) + 1, 511);
        int y0 = max((int)floorf(mny), 0), y1 = min((int)floorf(mxy) + 1, 511);
        Rx0[i - 1] = x0; Rx1[i - 1] = x1; Ry0[i - 1] = y0; Ry1[i - 1] = y1;
        if (x1 < x0 || y1 < y0) { empty = true; break; }
    }

    if (empty) {
        // any empty source region => tile is exactly zero
        int lx = tid & 31;
        for (int ly = tid >> 5; ly < TS; ly += 8)
            gout[(ty0 + ly) * 512 + tx0 + lx] = 0.f;
        return;
    }

    int w2 = Rx1[2] - Rx0[2] + 1, h2 = Ry1[2] - Ry0[2] + 1;
    int w3 = Rx1[3] - Rx0[3] + 1, h3 = Ry1[3] - Ry0[3] + 1;
    int w4 = Rx1[4] - Rx0[4] + 1, h4 = Ry1[4] - Ry0[4] + 1;
    int w5 = Rx1[5] - Rx0[5] + 1, h5 = Ry1[5] - Ry0[5] + 1;

    // ---- stage 2 (translate), source = global input with exact x-flip ----
    for (int ly = tid >> 5; ly < h2; ly += 8) {
        float py = (float)(Ry0[2] + ly);
        float fy = py - 10.24f;
        float yf = floorf(fy);
        float wy1 = fy - yf, wy0 = 1.f - wy1;
        int y0 = (int)yf, y1 = y0 + 1;
        bool vy0 = (unsigned)y0 < 512u, vy1 = (unsigned)y1 < 512u;
        int r0 = iclamp511(y0) * 512, r1 = iclamp511(y1) * 512;
        for (int lx = tid & 31; lx < w2; lx += 32) {
            float px = (float)(Rx0[2] + lx);
            float fx = px + 15.36f;
            float xf = floorf(fx);
            float wx1 = fx - xf, wx0 = 1.f - wx1;
            int x0 = (int)xf, x1 = x0 + 1;
            bool vx0 = (unsigned)x0 < 512u, vx1 = (unsigned)x1 < 512u;
            int xc0 = 511 - iclamp511(x0), xc1 = 511 - iclamp511(x1); // mirror fold
            float v00 = gin[r0 + xc0]; if (!(vx0 && vy0)) v00 = 0.f;
            float v01 = gin[r0 + xc1]; if (!(vx1 && vy0)) v01 = 0.f;
            float v10 = gin[r1 + xc0]; if (!(vx0 && vy1)) v10 = 0.f;
            float v11 = gin[r1 + xc1]; if (!(vx1 && vy1)) v11 = 0.f;
            bufA[ly * w2 + lx] = v00 * (wy0 * wx0) + v01 * (wy0 * wx1)
                               + v10 * (wy1 * wx0) + v11 * (wy1 * wx1);
        }
    }
    __syncthreads();

    // ---- stage 3 (scale): bufA(R2) -> bufB(R3) ----
    eval_lds<true>(tid, 1.1f, 0.f, 255.5f - 255.5f * 1.1f,
                        0.f, 0.95f, 255.5f - 255.5f * 0.95f,
                   bufA, Rx0[2], Ry0[2], w2, bufB, Rx0[3], Ry0[3], w3, h3);
    __syncthreads();

    // ---- stage 4 (zoom): bufB(R3) -> bufA(R4) ----
    eval_lds<true>(tid, 0.9f, 0.f, 255.5f - 255.5f * 0.9f,
                        0.f, 0.9f, 255.5f - 255.5f * 0.9f,
                   bufB, Rx0[3], Ry0[3], w3, bufA, Rx0[4], Ry0[4], w4, h4);
    __syncthreads();

    // ---- stage 5 (rotate): bufA(R4) -> bufB(R5) ----
    eval_lds<false>(tid, CR, -SR, 255.5f - 255.5f * (CR - SR),
                         SR, CR, 255.5f - 255.5f * (SR + CR),
                    bufA, Rx0[4], Ry0[4], w4, bufB, Rx0[5], Ry0[5], w5, h5);
    __syncthreads();

    // ---- stage 6 (shear): bufB(R5) -> global output tile ----
    {
        int sx0 = Rx0[5], sy0 = Ry0[5], sw = w5;
        int lx = tid & 31;
        for (int ly = tid >> 5; ly < TS; ly += 8) {
            float py = (float)(ty0 + ly);
            float fyb = py + (255.5f - 255.5f * 0.97f);
            float fxb = 0.05f * py + (255.5f - 255.5f * 1.05f);
            float px = (float)(tx0 + lx);
            float fx = px + fxb;
            float fy = -0.03f * px + fyb;
            float xf = floorf(fx), yf = floorf(fy);
            float wx1 = fx - xf, wx0 = 1.f - wx1;
            float wy1 = fy - yf, wy0 = 1.f - wy1;
            int x0 = (int)xf, x1 = x0 + 1, y0 = (int)yf, y1 = y0 + 1;
            bool vx0 = (unsigned)x0 < 512u, vx1 = (unsigned)x1 < 512u;
            bool vy0 = (unsigned)y0 < 512u, vy1 = (unsigned)y1 < 512u;
            int xc0 = iclamp511(x0) - sx0, xc1 = iclamp511(x1) - sx0;
            int r0 = (iclamp511(y0) - sy0) * sw, r1 = (iclamp511(y1) - sy0) * sw;
            float v00 = bufB[r0 + xc0]; if (!(vx0 && vy0)) v00 = 0.f;
            float v01 = bufB[r0 + xc1]; if (!(vx1 && vy0)) v01 = 0.f;
            float v10 = bufB[r1 + xc0]; if (!(vx0 && vy1)) v10 = 0.f;
            float v11 = bufB[r1 + xc1]; if (!(vx1 && vy1)) v11 = 0.f;
            gout[(ty0 + ly) * 512 + tx0 + lx] =
                v00 * (wy0 * wx0) + v01 * (wy0 * wx1)
              + v10 * (wy1 * wx0) + v11 * (wy1 * wx1);
        }
    }
}

// Compose the 6 nearest-neighbor integer maps (exact vs sequential resampling).
// UNCHANGED from the passing round-1 kernel (label path bit-exactness).
__global__ void compose_nearest_map(int* __restrict__ map) {
    int p = blockIdx.x * blockDim.x + threadIdx.x;
    if (p >= HW) return;

    const float TH[6][6] = {
        { 1.0f,  0.05f, 0.0f,  -0.03f, 1.0f,  0.0f },   // shear
        { CR,    -SR,   0.0f,   SR,    CR,    0.0f },   // rotate
        { 0.9f,  0.0f,  0.0f,   0.0f,  0.9f,  0.0f },   // zoom
        { 1.1f,  0.0f,  0.0f,   0.0f,  0.95f, 0.0f },   // scale
        { 1.0f,  0.0f,  0.06f,  0.0f,  1.0f, -0.04f },  // translate
        { -1.0f, 0.0f,  0.0f,   0.0f,  1.0f,  0.0f },   // mirror
    };

    int cx = p & 511;
    int cy = p >> 9;
    bool valid = true;
    #pragma unroll
    for (int s = 0; s < 6; ++s) {
        if (!valid) break;
        float x = (cx + 0.5f) * (2.0f / 512.0f) - 1.0f;
        float y = (cy + 0.5f) * (2.0f / 512.0f) - 1.0f;
        float gx = TH[s][0] * x + TH[s][1] * y + TH[s][2];
        float gy = TH[s][3] * x + TH[s][4] * y + TH[s][5];
        float ix = ((gx + 1.0f) * 512.0f - 1.0f) * 0.5f;
        float iy = ((gy + 1.0f) * 512.0f - 1.0f) * 0.5f;
        float xr = rintf(ix);
        float yr = rintf(iy);
        if (xr < 0.0f || xr > 511.0f || yr < 0.0f || yr > 511.0f) {
            valid = false;
        } else {
            cx = (int)xr;
            cy = (int)yr;
        }
    }
    map[p] = valid ? (cy * 512 + cx) : -1;
}

// Apply composed nearest map, 2D-tiled per plane for gather locality.
__global__ __launch_bounds__(256) void gather_label(const float* __restrict__ in,
                                                    const int* __restrict__ map,
                                                    float* __restrict__ out) {
    int b = blockIdx.x;
    int plane = b >> 8;
    int tile = b & 255;
    int tx0 = (tile & 15) * TS, ty0 = (tile >> 4) * TS;
    const float* gin = in + plane * HW;
    float* gout = out + plane * HW;
    int lx = threadIdx.x & 31;
    for (int ly = threadIdx.x >> 5; ly < TS; ly += 8) {
        int p = (ty0 + ly) * 512 + tx0 + lx;
        int m = map[p];
        gout[p] = (m >= 0) ? gin[m] : 0.f;
    }
}

extern "C" void kernel_launch(void* const* d_in, const int* in_sizes, int n_in,
                              void* d_out, int out_size, void* d_ws, size_t ws_size,
                              hipStream_t stream) {
    const float* img_in = (const float*)d_in[0];
    const float* lab_in = (const float*)d_in[1];
    float* out_img = (float*)d_out;           // first TOTAL floats
    float* out_lab = (float*)d_out + TOTAL;   // second TOTAL floats
    int* map = (int*)d_ws;                    // HW ints

    const int BLK = 256;
    const int NB = 48 * 256;                  // planes x tiles

    compose_nearest_map<<<(HW + BLK - 1) / BLK, BLK, 0, stream>>>(map);
    gather_label<<<NB, BLK, 0, stream>>>(lab_in, map, out_lab);
    fused_img<<<NB, BLK, 0, stream>>>(img_in, out_img);
}

// Round 3
// 130.449 us; speedup vs baseline: 2.1109x; 2.1109x over previous
//
#include <hip/hip_runtime.h>
#include <math.h>

#define HW 262144            // 512*512
#define TOTAL 12582912       // 48 planes * HW
#define TS 32
#define BUFA_SZ 2304         // holds R2 (<=51x43=2193) and R4 (<=48x47=2256)
#define BUFB_SZ 2048         // holds R3 (<=45x44=1980) and R5 (<=35x34=1190)

#define CR 0.8910065241883679f   // cos(27 deg)
#define SR 0.45399049973954675f  // sin(27 deg)

struct Box { int x0, x1, y0, y1; };

// dest box -> source bbox (unclipped, +1 halo for the x0+1 tap)
__device__ __forceinline__ Box back_box(Box d, float A, float B, float C,
                                        float D, float E, float F) {
    float xa = (float)d.x0, xb = (float)d.x1, ya = (float)d.y0, yb = (float)d.y1;
    float mnx = fminf(A * xa, A * xb) + fminf(B * ya, B * yb) + C;
    float mxx = fmaxf(A * xa, A * xb) + fmaxf(B * ya, B * yb) + C;
    float mny = fminf(D * xa, D * xb) + fminf(E * ya, E * yb) + F;
    float mxy = fmaxf(D * xa, D * xb) + fmaxf(E * ya, E * yb) + F;
    Box s;
    s.x0 = (int)floorf(mnx); s.x1 = (int)floorf(mxx) + 1;
    s.y0 = (int)floorf(mny); s.y1 = (int)floorf(mxy) + 1;
    return s;
}

// LDS -> LDS bilinear stage over an unclipped region. Source buffer covers all
// taps (bbox construction) and already holds zeros at out-of-image pixels, so
// taps need no validity logic; int clamps are fp-edge defense only (bilinear
// is continuous there). Out-of-image DEST pixels are written as 0.
template <bool AXIS>
__device__ __forceinline__ void stage_lds(int tid,
    float A, float B, float C, float D, float E, float F,
    const float* __restrict__ src, int sx0, int sy0, int sw, int sh,
    float* __restrict__ dst, int dx0, int dy0, int dw, int dh)
{
    int total = dw * dh;
    float rw = 1.0f / (float)dw;
    float Cs = C - (float)sx0;   // fold source origin into constants
    float Fs = F - (float)sy0;
    for (int i = tid; i < total; i += 256) {
        int ly = (int)(((float)i + 0.5f) * rw);  // exact for i < 2^23, w <= 64
        int lx = i - ly * dw;
        int pxi = dx0 + lx, pyi = dy0 + ly;
        float px = (float)pxi, py = (float)pyi;
        float fx = AXIS ? fmaf(A, px, Cs) : fmaf(A, px, fmaf(B, py, Cs));
        float fy = AXIS ? fmaf(E, py, Fs) : fmaf(D, px, fmaf(E, py, Fs));
        float xf = floorf(fx), yf = floorf(fy);
        float wx = fx - xf, wy = fy - yf;
        int x0 = min(max((int)xf, 0), sw - 2);
        int y0 = min(max((int)yf, 0), sh - 2);
        const float* s = src + y0 * sw + x0;
        float v00 = s[0], v01 = s[1];        // -> ds_read2_b32
        float v10 = s[sw], v11 = s[sw + 1];  // -> ds_read2_b32
        float a0 = fmaf(wx, v01 - v00, v00);
        float a1 = fmaf(wx, v11 - v10, v10);
        float val = fmaf(wy, a1 - a0, a0);
        if ((unsigned)pxi >= 512u || (unsigned)pyi >= 512u) val = 0.f;
        dst[i] = val;
    }
}

// Compose the 6 nearest-neighbor integer maps (exact vs sequential resampling).
__global__ void compose_nearest_map(int* __restrict__ map) {
    int p = blockIdx.x * blockDim.x + threadIdx.x;
    if (p >= HW) return;
    const float TH[6][6] = {
        { 1.0f,  0.05f, 0.0f,  -0.03f, 1.0f,  0.0f },   // shear
        { CR,    -SR,   0.0f,   SR,    CR,    0.0f },   // rotate
        { 0.9f,  0.0f,  0.0f,   0.0f,  0.9f,  0.0f },   // zoom
        { 1.1f,  0.0f,  0.0f,   0.0f,  0.95f, 0.0f },   // scale
        { 1.0f,  0.0f,  0.06f,  0.0f,  1.0f, -0.04f },  // translate
        { -1.0f, 0.0f,  0.0f,   0.0f,  1.0f,  0.0f },   // mirror
    };
    int cx = p & 511, cy = p >> 9;
    bool valid = true;
    #pragma unroll
    for (int s = 0; s < 6; ++s) {
        if (!valid) break;
        float x = (cx + 0.5f) * (2.0f / 512.0f) - 1.0f;
        float y = (cy + 0.5f) * (2.0f / 512.0f) - 1.0f;
        float gx = TH[s][0] * x + TH[s][1] * y + TH[s][2];
        float gy = TH[s][3] * x + TH[s][4] * y + TH[s][5];
        float ix = ((gx + 1.0f) * 512.0f - 1.0f) * 0.5f;
        float iy = ((gy + 1.0f) * 512.0f - 1.0f) * 0.5f;
        float xr = rintf(ix), yr = rintf(iy);
        if (xr < 0.0f || xr > 511.0f || yr < 0.0f || yr > 511.0f) valid = false;
        else { cx = (int)xr; cy = (int)yr; }
    }
    map[p] = valid ? (cy * 512 + cx) : -1;
}

// Label gather + all 6 fused img stages, one block per (plane, 32x32 tile).
__global__ __launch_bounds__(256, 6) void fused_all(
    const float* __restrict__ img, const float* __restrict__ lab,
    const int* __restrict__ map, float* __restrict__ oimg,
    float* __restrict__ olab)
{
    __shared__ float bufA[BUFA_SZ];
    __shared__ float bufB[BUFB_SZ];
    int tid = threadIdx.x;
    int b = blockIdx.x;
    int plane = b >> 8, tile = b & 255;
    int tx0 = (tile & 15) * TS, ty0 = (tile >> 4) * TS;
    const float* gin = img + plane * HW;
    const float* lin = lab + plane * HW;
    float* go = oimg + plane * HW;
    float* lo = olab + plane * HW;

    // ---- label tile (independent; scattered loads overlap img VALU work) ----
    for (int ii = tid; ii < TS * TS; ii += 256) {
        int p = (ty0 + (ii >> 5)) * 512 + tx0 + (ii & 31);
        int m = map[p];
        lo[p] = (m >= 0) ? lin[m] : 0.f;
    }

    // ---- region chain (uniform across threads) ----
    Box R6 = {tx0, tx0 + TS - 1, ty0, ty0 + TS - 1};
    Box R5 = back_box(R6, 1.0f, 0.05f, -12.775f, -0.03f, 1.0f, 7.665f);         // shear
    Box R4 = back_box(R5, CR, -SR, 255.5f * (1.0f - CR + SR),
                          SR,  CR, 255.5f * (1.0f - SR - CR));                  // rotate
    Box R3 = back_box(R4, 0.9f, 0.0f, 25.55f, 0.0f, 0.9f, 25.55f);              // zoom
    Box R2 = back_box(R3, 1.1f, 0.0f, -25.55f, 0.0f, 0.95f, 12.775f);           // scale

    bool dead = (R2.x1 < 0 || R2.x0 > 511 || R2.y1 < 0 || R2.y0 > 511)
             || (R3.x1 < 0 || R3.x0 > 511 || R3.y1 < 0 || R3.y0 > 511)
             || (R4.x1 < 0 || R4.x0 > 511 || R4.y1 < 0 || R4.y0 > 511)
             || (R5.x1 < 0 || R5.x0 > 511 || R5.y1 < 0 || R5.y0 > 511);
    if (dead) {  // some stage's needed region is fully out-of-image => zeros
        for (int ii = tid; ii < TS * TS; ii += 256)
            go[(ty0 + (ii >> 5)) * 512 + tx0 + (ii & 31)] = 0.f;
        return;
    }

    int w2 = R2.x1 - R2.x0 + 1, h2 = R2.y1 - R2.y0 + 1;
    int w3 = R3.x1 - R3.x0 + 1, h3 = R3.y1 - R3.y0 + 1;
    int w4 = R4.x1 - R4.x0 + 1, h4 = R4.y1 - R4.y0 + 1;
    int w5 = R5.x1 - R5.x0 + 1, h5 = R5.y1 - R5.y0 + 1;

    // ---- stage 2 (translate) from GLOBAL with exact mirror fold -> bufA(R2) ----
    {
        int total = w2 * h2;
        float rw = 1.0f / (float)w2;
        for (int i = tid; i < total; i += 256) {
            int ly = (int)(((float)i + 0.5f) * rw);
            int lx = i - ly * w2;
            int pxi = R2.x0 + lx, pyi = R2.y0 + ly;
            float val = 0.f;
            if ((unsigned)pxi < 512u && (unsigned)pyi < 512u) {
                float fx = (float)pxi + 15.36f;
                float fy = (float)pyi - 10.24f;
                float xf = floorf(fx), yf = floorf(fy);
                float wx = fx - xf, wy = fy - yf;
                int x0 = (int)xf, y0 = (int)yf;
                bool vx0 = (unsigned)x0 < 512u, vx1 = (unsigned)(x0 + 1) < 512u;
                bool vy0 = (unsigned)y0 < 512u, vy1 = (unsigned)(y0 + 1) < 512u;
                int xm0 = 511 - min(max(x0, 0), 511);
                int xm1 = 511 - min(max(x0 + 1, 0), 511);
                int r0 = min(max(y0, 0), 511) * 512;
                int r1 = min(max(y0 + 1, 0), 511) * 512;
                float v00 = (vx0 && vy0) ? gin[r0 + xm0] : 0.f;
                float v01 = (vx1 && vy0) ? gin[r0 + xm1] : 0.f;
                float v10 = (vx0 && vy1) ? gin[r1 + xm0] : 0.f;
                float v11 = (vx1 && vy1) ? gin[r1 + xm1] : 0.f;
                float a0 = fmaf(wx, v01 - v00, v00);
                float a1 = fmaf(wx, v11 - v10, v10);
                val = fmaf(wy, a1 - a0, a0);
            }
            bufA[i] = val;
        }
    }
    __syncthreads();

    // ---- stage 3 (scale): bufA(R2) -> bufB(R3) ----
    stage_lds<true>(tid, 1.1f, 0.0f, -25.55f, 0.0f, 0.95f, 12.775f,
                    bufA, R2.x0, R2.y0, w2, h2, bufB, R3.x0, R3.y0, w3, h3);
    __syncthreads();

    // ---- stage 4 (zoom): bufB(R3) -> bufA(R4) ----
    stage_lds<true>(tid, 0.9f, 0.0f, 25.55f, 0.0f, 0.9f, 25.55f,
                    bufB, R3.x0, R3.y0, w3, h3, bufA, R4.x0, R4.y0, w4, h4);
    __syncthreads();

    // ---- stage 5 (rotate): bufA(R4) -> bufB(R5) ----
    stage_lds<false>(tid, CR, -SR, 255.5f * (1.0f - CR + SR),
                          SR,  CR, 255.5f * (1.0f - SR - CR),
                     bufA, R4.x0, R4.y0, w4, h4, bufB, R5.x0, R5.y0, w5, h5);
    __syncthreads();

    // ---- stage 6 (shear): bufB(R5) -> global output tile ----
    {
        float Cs = -12.775f - (float)R5.x0;
        float Fs = 7.665f - (float)R5.y0;
        for (int ii = tid; ii < TS * TS; ii += 256) {
            int lx = ii & 31, ly = ii >> 5;
            float px = (float)(tx0 + lx), py = (float)(ty0 + ly);
            float fx = fmaf(0.05f, py, Cs) + px;
            float fy = fmaf(-0.03f, px, Fs) + py;
            float xf = floorf(fx), yf = floorf(fy);
            float wx = fx - xf, wy = fy - yf;
            int x0 = min(max((int)xf, 0), w5 - 2);
            int y0 = min(max((int)yf, 0), h5 - 2);
            const float* s = bufB + y0 * w5 + x0;
            float v00 = s[0], v01 = s[1];
            float v10 = s[w5], v11 = s[w5 + 1];
            float a0 = fmaf(wx, v01 - v00, v00);
            float a1 = fmaf(wx, v11 - v10, v10);
            go[(ty0 + ly) * 512 + tx0 + lx] = fmaf(wy, a1 - a0, a0);
        }
    }
}

extern "C" void kernel_launch(void* const* d_in, const int* in_sizes, int n_in,
                              void* d_out, int out_size, void* d_ws, size_t ws_size,
                              hipStream_t stream) {
    const float* img_in = (const float*)d_in[0];
    const float* lab_in = (const float*)d_in[1];
    float* out_img = (float*)d_out;
    float* out_lab = (float*)d_out + TOTAL;
    int* map = (int*)d_ws;

    const int BLK = 256;
    compose_nearest_map<<<(HW + BLK - 1) / BLK, BLK, 0, stream>>>(map);
    fused_all<<<48 * 256, BLK, 0, stream>>>(img_in, lab_in, map, out_img, out_lab);
}

// Round 4
// 104.511 us; speedup vs baseline: 2.6348x; 1.2482x over previous
//
#include <hip/hip_runtime.h>
#include <math.h>

#define HW 262144            // 512*512
#define TOTAL 12582912       // 48 planes * HW
#define TS 32

#define CR 0.8910065241883679f   // cos(27 deg)
#define SR 0.45399049973954675f  // sin(27 deg)

// Fixed padded region dims (tile-position-independent spans +1..2 margin)
#define W2 52
#define H2 44
#define W3 46
#define H3 45
#define W4 49
#define H4 48
#define W5 36
#define H5 35
#define BUFA_SZ 2352   // max(W2*H2=2288, W4*H4=2352)
#define BUFB_SZ 2070   // max(W3*H3=2070, W5*H5=1260)

struct Box { int x0, x1, y0, y1; };

// dest box -> source bbox (unclipped, +1 halo for the +1 taps)
__device__ __forceinline__ Box back_box(Box d, float A, float B, float C,
                                        float D, float E, float F) {
    float xa = (float)d.x0, xb = (float)d.x1, ya = (float)d.y0, yb = (float)d.y1;
    float mnx = fminf(A * xa, A * xb) + fminf(B * ya, B * yb) + C;
    float mxx = fmaxf(A * xa, A * xb) + fmaxf(B * ya, B * yb) + C;
    float mny = fminf(D * xa, D * xb) + fminf(E * ya, E * yb) + F;
    float mxy = fmaxf(D * xa, D * xb) + fmaxf(E * ya, E * yb) + F;
    Box s;
    s.x0 = (int)floorf(mnx); s.x1 = (int)floorf(mxx) + 1;
    s.y0 = (int)floorf(mny); s.y1 = (int)floorf(mxy) + 1;
    return s;
}

// LDS -> LDS bilinear stage, compile-time geometry. Source buffer covers all
// taps and holds zeros at out-of-image pixels (written by prior stage), so
// taps need no validity logic; clamps vs constants are fp-edge defense only.
// Out-of-image DEST pixels are written as 0 (consumed as zeros downstream).
template <int SW, int SH, int DW, int DTOT, bool AXIS>
__device__ __forceinline__ void stage_lds(int tid,
    float A, float B, float Cs, float D, float E, float Fs,
    const float* __restrict__ src, float* __restrict__ dst,
    int dx0, int dy0)
{
    for (int i = tid; i < DTOT; i += 256) {
        int ly = i / DW;             // compile-time divisor -> magic mul
        int lx = i - ly * DW;
        int pxi = dx0 + lx, pyi = dy0 + ly;
        float px = (float)pxi, py = (float)pyi;
        float fx = AXIS ? fmaf(A, px, Cs) : fmaf(A, px, fmaf(B, py, Cs));
        float fy = AXIS ? fmaf(E, py, Fs) : fmaf(D, px, fmaf(E, py, Fs));
        float xf = floorf(fx), yf = floorf(fy);
        float wx = fx - xf, wy = fy - yf;
        int x0 = min(max((int)xf, 0), SW - 2);
        int y0 = min(max((int)yf, 0), SH - 2);
        const float* s = src + y0 * SW + x0;
        float v00 = s[0], v01 = s[1];          // ds_read2_b32
        float v10 = s[SW], v11 = s[SW + 1];    // ds_read2_b32
        float a0 = fmaf(wx, v01 - v00, v00);
        float a1 = fmaf(wx, v11 - v10, v10);
        float val = fmaf(wy, a1 - a0, a0);
        if ((unsigned)pxi >= 512u || (unsigned)pyi >= 512u) val = 0.f;
        dst[i] = val;
    }
}

// Compose the 6 nearest-neighbor integer maps (exact vs sequential resampling).
__global__ void compose_nearest_map(int* __restrict__ map) {
    int p = blockIdx.x * blockDim.x + threadIdx.x;
    if (p >= HW) return;
    const float TH[6][6] = {
        { 1.0f,  0.05f, 0.0f,  -0.03f, 1.0f,  0.0f },   // shear
        { CR,    -SR,   0.0f,   SR,    CR,    0.0f },   // rotate
        { 0.9f,  0.0f,  0.0f,   0.0f,  0.9f,  0.0f },   // zoom
        { 1.1f,  0.0f,  0.0f,   0.0f,  0.95f, 0.0f },   // scale
        { 1.0f,  0.0f,  0.06f,  0.0f,  1.0f, -0.04f },  // translate
        { -1.0f, 0.0f,  0.0f,   0.0f,  1.0f,  0.0f },   // mirror
    };
    int cx = p & 511, cy = p >> 9;
    bool valid = true;
    #pragma unroll
    for (int s = 0; s < 6; ++s) {
        if (!valid) break;
        float x = (cx + 0.5f) * (2.0f / 512.0f) - 1.0f;
        float y = (cy + 0.5f) * (2.0f / 512.0f) - 1.0f;
        float gx = TH[s][0] * x + TH[s][1] * y + TH[s][2];
        float gy = TH[s][3] * x + TH[s][4] * y + TH[s][5];
        float ix = ((gx + 1.0f) * 512.0f - 1.0f) * 0.5f;
        float iy = ((gy + 1.0f) * 512.0f - 1.0f) * 0.5f;
        float xr = rintf(ix), yr = rintf(iy);
        if (xr < 0.0f || xr > 511.0f || yr < 0.0f || yr > 511.0f) valid = false;
        else { cx = (int)xr; cy = (int)yr; }
    }
    map[p] = valid ? (cy * 512 + cx) : -1;
}

// Label gather + all 6 fused img stages, one block per (plane, 32x32 tile).
__global__ __launch_bounds__(256, 8) void fused_all(
    const float* __restrict__ img, const float* __restrict__ lab,
    const int* __restrict__ map, float* __restrict__ oimg,
    float* __restrict__ olab)
{
    __shared__ float bufA[BUFA_SZ];
    __shared__ float bufB[BUFB_SZ];
    int tid = threadIdx.x;
    int b = blockIdx.x;
    int plane = b >> 8, tile = b & 255;
    int tx0 = (tile & 15) * TS, ty0 = (tile >> 4) * TS;
    const float* gin = img + plane * HW;
    const float* lin = lab + plane * HW;
    float* go = oimg + plane * HW;
    float* lo = olab + plane * HW;

    // ---- label tile (independent; scattered loads overlap img work) ----
    for (int ii = tid; ii < TS * TS; ii += 256) {
        int p = (ty0 + (ii >> 5)) * 512 + tx0 + (ii & 31);
        int m = map[p];
        float v = (m >= 0) ? lin[m] : 0.f;
        __builtin_nontemporal_store(v, &lo[p]);
    }

    // ---- region chain (uniform across threads) ----
    Box R6 = {tx0, tx0 + TS - 1, ty0, ty0 + TS - 1};
    Box R5 = back_box(R6, 1.0f, 0.05f, -12.775f, -0.03f, 1.0f, 7.665f);   // shear
    R5.x1 = min(R5.x1, R5.x0 + W5 - 1); R5.y1 = min(R5.y1, R5.y0 + H5 - 1);
    Box R4 = back_box(R5, CR, -SR, 255.5f * (1.0f - CR + SR),
                          SR,  CR, 255.5f * (1.0f - SR - CR));            // rotate
    R4.x1 = min(R4.x1, R4.x0 + W4 - 1); R4.y1 = min(R4.y1, R4.y0 + H4 - 1);
    Box R3 = back_box(R4, 0.9f, 0.0f, 25.55f, 0.0f, 0.9f, 25.55f);        // zoom
    R3.x1 = min(R3.x1, R3.x0 + W3 - 1); R3.y1 = min(R3.y1, R3.y0 + H3 - 1);
    Box R2 = back_box(R3, 1.1f, 0.0f, -25.55f, 0.0f, 0.95f, 12.775f);     // scale

    bool dead = (R2.x1 < 0 || R2.x0 > 511 || R2.y1 < 0 || R2.y0 > 511)
             || (R3.x1 < 0 || R3.x0 > 511 || R3.y1 < 0 || R3.y0 > 511)
             || (R4.x1 < 0 || R4.x0 > 511 || R4.y1 < 0 || R4.y0 > 511)
             || (R5.x1 < 0 || R5.x0 > 511 || R5.y1 < 0 || R5.y0 > 511);
    if (dead) {
        for (int ii = tid; ii < TS * TS; ii += 256)
            __builtin_nontemporal_store(0.f,
                &go[(ty0 + (ii >> 5)) * 512 + tx0 + (ii & 31)]);
        return;
    }

    // ---- stage 2 (translate) from GLOBAL with exact mirror fold -> bufA ----
    // Integer px => constant weights wx=0.36, wy=0.76; tap+dest validity folds
    // into single unsigned range checks per weight.
    for (int i = tid; i < W2 * H2; i += 256) {
        int ly = i / W2;
        int lx = i - ly * W2;
        int pxi = R2.x0 + lx, pyi = R2.y0 + ly;
        float wx0m = ((unsigned)pxi <= 496u) ? 0.64f : 0.0f;
        float wx1m = ((unsigned)pxi <= 495u) ? 0.36f : 0.0f;
        float wy0m = ((unsigned)(pyi - 11) <= 500u) ? 0.24f : 0.0f;
        float wy1m = ((unsigned)(pyi - 10) <= 501u) ? 0.76f : 0.0f;
        int xc0 = min(max(496 - pxi, 0), 511);
        int xc1 = min(max(495 - pxi, 0), 511);
        int r0 = min(max(pyi - 11, 0), 511) << 9;
        int r1 = min(max(pyi - 10, 0), 511) << 9;
        float v00 = gin[r0 + xc0], v01 = gin[r0 + xc1];
        float v10 = gin[r1 + xc0], v11 = gin[r1 + xc1];
        float h0 = fmaf(wx1m, v01, wx0m * v00);
        float h1 = fmaf(wx1m, v11, wx0m * v10);
        bufA[i] = fmaf(wy1m, h1, wy0m * h0);
    }
    __syncthreads();

    // ---- stage 3 (scale): bufA(R2) -> bufB(R3) ----
    stage_lds<W2, H2, W3, W3 * H3, true>(tid,
        1.1f, 0.0f, -25.55f - (float)R2.x0,
        0.0f, 0.95f, 12.775f - (float)R2.y0,
        bufA, bufB, R3.x0, R3.y0);
    __syncthreads();

    // ---- stage 4 (zoom): bufB(R3) -> bufA(R4) ----
    stage_lds<W3, H3, W4, W4 * H4, true>(tid,
        0.9f, 0.0f, 25.55f - (float)R3.x0,
        0.0f, 0.9f, 25.55f - (float)R3.y0,
        bufB, bufA, R4.x0, R4.y0);
    __syncthreads();

    // ---- stage 5 (rotate): bufA(R4) -> bufB(R5) ----
    stage_lds<W4, H4, W5, W5 * H5, false>(tid,
        CR, -SR, 255.5f * (1.0f - CR + SR) - (float)R4.x0,
        SR,  CR, 255.5f * (1.0f - SR - CR) - (float)R4.y0,
        bufA, bufB, R5.x0, R5.y0);
    __syncthreads();

    // ---- stage 6 (shear): bufB(R5) -> global output tile ----
    {
        float Cs = -12.775f - (float)R5.x0;
        float Fs = 7.665f - (float)R5.y0;
        for (int ii = tid; ii < TS * TS; ii += 256) {
            int lx = ii & 31, ly = ii >> 5;
            float px = (float)(tx0 + lx), py = (float)(ty0 + ly);
            float fx = fmaf(0.05f, py, Cs) + px;
            float fy = fmaf(-0.03f, px, Fs) + py;
            float xf = floorf(fx), yf = floorf(fy);
            float wx = fx - xf, wy = fy - yf;
            int x0 = min(max((int)xf, 0), W5 - 2);
            int y0 = min(max((int)yf, 0), H5 - 2);
            const float* s = bufB + y0 * W5 + x0;
            float v00 = s[0], v01 = s[1];
            float v10 = s[W5], v11 = s[W5 + 1];
            float a0 = fmaf(wx, v01 - v00, v00);
            float a1 = fmaf(wx, v11 - v10, v10);
            float val = fmaf(wy, a1 - a0, a0);
            __builtin_nontemporal_store(val, &go[(ty0 + ly) * 512 + tx0 + lx]);
        }
    }
}

extern "C" void kernel_launch(void* const* d_in, const int* in_sizes, int n_in,
                              void* d_out, int out_size, void* d_ws, size_t ws_size,
                              hipStream_t stream) {
    const float* img_in = (const float*)d_in[0];
    const float* lab_in = (const float*)d_in[1];
    float* out_img = (float*)d_out;
    float* out_lab = (float*)d_out + TOTAL;
    int* map = (int*)d_ws;

    const int BLK = 256;
    compose_nearest_map<<<(HW + BLK - 1) / BLK, BLK, 0, stream>>>(map);
    fused_all<<<48 * 256, BLK, 0, stream>>>(img_in, lab_in, map, out_img, out_lab);
}

// Round 5
// 89.636 us; speedup vs baseline: 3.0720x; 1.1659x over previous
//
#include <hip/hip_runtime.h>
#include <math.h>

#define HW 262144            // 512*512
#define TOTAL 12582912       // 48 planes * HW
#define TS 32
#define NT 512               // threads per block

#define CR 0.8910065241883679f   // cos(27 deg)
#define SR 0.45399049973954675f  // sin(27 deg)

// rotate pixel-space constants
#define K5CX (255.5f * (1.0f - CR + SR))
#define K5CY (255.5f * (1.0f - SR - CR))

// Fixed padded region dims (>= max true span at any tile position; verified
// by span arithmetic: R5<=35x34, R4<=48x47, R3<=45x44, R2<=51x44)
#define W2 52
#define H2 44
#define W3 46
#define H3 45
#define W4 49
#define H4 48
#define W5 36
#define H5 35
#define BUFA_SZ 2352   // max(W2*H2=2288, W4*H4=2352)
#define BUFB_SZ 2070   // max(W3*H3=2070, W5*H5=1260)

struct Box { int x0, x1, y0, y1; };

__device__ __forceinline__ Box back_box(Box d, float A, float B, float C,
                                        float D, float E, float F) {
    float xa = (float)d.x0, xb = (float)d.x1, ya = (float)d.y0, yb = (float)d.y1;
    float mnx = fminf(A * xa, A * xb) + fminf(B * ya, B * yb) + C;
    float mxx = fmaxf(A * xa, A * xb) + fmaxf(B * ya, B * yb) + C;
    float mny = fminf(D * xa, D * xb) + fminf(E * ya, E * yb) + F;
    float mxy = fmaxf(D * xa, D * xb) + fmaxf(E * ya, E * yb) + F;
    Box s;
    s.x0 = (int)floorf(mnx); s.x1 = (int)floorf(mxx) + 1;
    s.y0 = (int)floorf(mny); s.y1 = (int)floorf(mxy) + 1;
    return s;
}

// ---- stage 2 (translate, mirror folded) single eval: global -> bufA ----
// Constant weights: wx=0.36 (taps at 496-pxi, 495-pxi), wy=0.76 (rows pyi-11, pyi-10)
template <bool INT>
__device__ __forceinline__ void s2_eval(int i, const float* __restrict__ gin,
                                        float* __restrict__ dst, int rx0, int ry0)
{
    int ly = i / W2;
    int lx = i - ly * W2;
    int pxi = rx0 + lx, pyi = ry0 + ly;
    if (INT) {
        int xc0 = 496 - pxi;               // in [1,496] guaranteed
        const float* g0 = gin + ((pyi - 11) << 9);
        float v00 = g0[xc0], v01 = g0[xc0 - 1];
        float v10 = g0[512 + xc0], v11 = g0[512 + xc0 - 1];
        float h0 = fmaf(0.36f, v01, 0.64f * v00);
        float h1 = fmaf(0.36f, v11, 0.64f * v10);
        dst[i] = fmaf(0.76f, h1, 0.24f * h0);
    } else {
        float wx0m = ((unsigned)pxi <= 496u) ? 0.64f : 0.0f;
        float wx1m = ((unsigned)pxi <= 495u) ? 0.36f : 0.0f;
        float wy0m = ((unsigned)(pyi - 11) <= 500u) ? 0.24f : 0.0f;
        float wy1m = ((unsigned)(pyi - 10) <= 501u) ? 0.76f : 0.0f;
        int xc0 = min(max(496 - pxi, 0), 511);
        int xc1 = min(max(495 - pxi, 0), 511);
        int r0 = min(max(pyi - 11, 0), 511) << 9;
        int r1 = min(max(pyi - 10, 0), 511) << 9;
        float v00 = gin[r0 + xc0], v01 = gin[r0 + xc1];
        float v10 = gin[r1 + xc0], v11 = gin[r1 + xc1];
        float h0 = fmaf(wx1m, v01, wx0m * v00);
        float h1 = fmaf(wx1m, v11, wx0m * v10);
        dst[i] = fmaf(wy1m, h1, wy0m * h0);
    }
}

// ---- LDS -> LDS bilinear stage single eval ----
// INT: taps guaranteed genuine & in-allocation (bbox + padding arithmetic);
// padding-cell overreads land inside the block's LDS and are never consumed.
template <int SW, int SH, int DW, bool AXIS, bool INT>
__device__ __forceinline__ void lds_eval(int i, float A, float B, float Cs,
    float D, float E, float Fs, const float* __restrict__ src,
    float* __restrict__ dst, int dx0, int dy0)
{
    int ly = i / DW;
    int lx = i - ly * DW;
    int pxi = dx0 + lx, pyi = dy0 + ly;
    float px = (float)pxi, py = (float)pyi;
    float fx = AXIS ? fmaf(A, px, Cs) : fmaf(A, px, fmaf(B, py, Cs));
    float fy = AXIS ? fmaf(E, py, Fs) : fmaf(D, px, fmaf(E, py, Fs));
    float xf = floorf(fx), yf = floorf(fy);
    float wx = fx - xf, wy = fy - yf;
    int x0 = (int)xf, y0 = (int)yf;
    if (!INT) { x0 = min(max(x0, 0), SW - 2); y0 = min(max(y0, 0), SH - 2); }
    const float* s = src + y0 * SW + x0;
    float v00 = s[0], v01 = s[1];
    float v10 = s[SW], v11 = s[SW + 1];
    float a0 = fmaf(wx, v01 - v00, v00);
    float a1 = fmaf(wx, v11 - v10, v10);
    float val = fmaf(wy, a1 - a0, a0);
    if (!INT) { if ((unsigned)pxi >= 512u || (unsigned)pyi >= 512u) val = 0.f; }
    dst[i] = val;
}

template <int SW, int SH, int DW, int DTOT, bool AXIS, bool INT>
__device__ __forceinline__ void stage_lds(int tid, float A, float B, float Cs,
    float D, float E, float Fs, const float* __restrict__ src,
    float* __restrict__ dst, int dx0, int dy0)
{
    constexpr int FULL = DTOT / NT;
    constexpr int TAIL = DTOT - FULL * NT;
    #pragma unroll
    for (int k = 0; k < FULL; ++k)
        lds_eval<SW, SH, DW, AXIS, INT>(tid + k * NT, A, B, Cs, D, E, Fs,
                                        src, dst, dx0, dy0);
    if (TAIL && tid < TAIL)
        lds_eval<SW, SH, DW, AXIS, INT>(tid + FULL * NT, A, B, Cs, D, E, Fs,
                                        src, dst, dx0, dy0);
}

// ---- stage 6 (shear) single eval: bufB(R5) -> global ----
template <bool INT>
__device__ __forceinline__ void s6_eval(int ii, const float* __restrict__ src,
    float* __restrict__ go, int tx0, int ty0, int sx0, int sy0)
{
    int lx = ii & 31, ly = ii >> 5;
    float px = (float)(tx0 + lx), py = (float)(ty0 + ly);
    float fx = fmaf(0.05f, py, -12.775f - (float)sx0) + px;
    float fy = fmaf(-0.03f, px, 7.665f - (float)sy0) + py;
    float xf = floorf(fx), yf = floorf(fy);
    float wx = fx - xf, wy = fy - yf;
    int x0 = (int)xf, y0 = (int)yf;
    if (!INT) { x0 = min(max(x0, 0), W5 - 2); y0 = min(max(y0, 0), H5 - 2); }
    const float* s = src + y0 * W5 + x0;
    float v00 = s[0], v01 = s[1];
    float v10 = s[W5], v11 = s[W5 + 1];
    float a0 = fmaf(wx, v01 - v00, v00);
    float a1 = fmaf(wx, v11 - v10, v10);
    float val = fmaf(wy, a1 - a0, a0);
    __builtin_nontemporal_store(val, &go[(ty0 + ly) * 512 + tx0 + lx]);
}

// ---- full img tile pipeline, templated on interior fast path ----
template <bool INT>
__device__ __forceinline__ void img_tile(int tid, const float* __restrict__ gin,
    float* __restrict__ go, int tx0, int ty0,
    Box R2, Box R3, Box R4, Box R5, float* bufA, float* bufB)
{
    // stage 2: global -> bufA(R2)
    {
        constexpr int FULL = (W2 * H2) / NT;          // 4
        constexpr int TAIL = W2 * H2 - FULL * NT;     // 240
        #pragma unroll
        for (int k = 0; k < FULL; ++k)
            s2_eval<INT>(tid + k * NT, gin, bufA, R2.x0, R2.y0);
        if (tid < TAIL) s2_eval<INT>(tid + FULL * NT, gin, bufA, R2.x0, R2.y0);
    }
    __syncthreads();
    // stage 3 (scale): bufA(R2) -> bufB(R3)
    stage_lds<W2, H2, W3, W3 * H3, true, INT>(tid,
        1.1f, 0.0f, -25.55f - (float)R2.x0,
        0.0f, 0.95f, 12.775f - (float)R2.y0, bufA, bufB, R3.x0, R3.y0);
    __syncthreads();
    // stage 4 (zoom): bufB(R3) -> bufA(R4)
    stage_lds<W3, H3, W4, W4 * H4, true, INT>(tid,
        0.9f, 0.0f, 25.55f - (float)R3.x0,
        0.0f, 0.9f, 25.55f - (float)R3.y0, bufB, bufA, R4.x0, R4.y0);
    __syncthreads();
    // stage 5 (rotate): bufA(R4) -> bufB(R5)
    stage_lds<W4, H4, W5, W5 * H5, false, INT>(tid,
        CR, -SR, K5CX - (float)R4.x0,
        SR,  CR, K5CY - (float)R4.y0, bufA, bufB, R5.x0, R5.y0);
    __syncthreads();
    // stage 6 (shear): bufB(R5) -> global tile
    {
        #pragma unroll
        for (int k = 0; k < (TS * TS) / NT; ++k)
            s6_eval<INT>(tid + k * NT, bufB, go, tx0, ty0, R5.x0, R5.y0);
    }
}

// Compose the 6 nearest-neighbor integer maps (exact vs sequential resampling).
__global__ void compose_nearest_map(int* __restrict__ map) {
    int p = blockIdx.x * blockDim.x + threadIdx.x;
    if (p >= HW) return;
    const float TH[6][6] = {
        { 1.0f,  0.05f, 0.0f,  -0.03f, 1.0f,  0.0f },   // shear
        { CR,    -SR,   0.0f,   SR,    CR,    0.0f },   // rotate
        { 0.9f,  0.0f,  0.0f,   0.0f,  0.9f,  0.0f },   // zoom
        { 1.1f,  0.0f,  0.0f,   0.0f,  0.95f, 0.0f },   // scale
        { 1.0f,  0.0f,  0.06f,  0.0f,  1.0f, -0.04f },  // translate
        { -1.0f, 0.0f,  0.0f,   0.0f,  1.0f,  0.0f },   // mirror
    };
    int cx = p & 511, cy = p >> 9;
    bool valid = true;
    #pragma unroll
    for (int s = 0; s < 6; ++s) {
        if (!valid) break;
        float x = (cx + 0.5f) * (2.0f / 512.0f) - 1.0f;
        float y = (cy + 0.5f) * (2.0f / 512.0f) - 1.0f;
        float gx = TH[s][0] * x + TH[s][1] * y + TH[s][2];
        float gy = TH[s][3] * x + TH[s][4] * y + TH[s][5];
        float ix = ((gx + 1.0f) * 512.0f - 1.0f) * 0.5f;
        float iy = ((gy + 1.0f) * 512.0f - 1.0f) * 0.5f;
        float xr = rintf(ix), yr = rintf(iy);
        if (xr < 0.0f || xr > 511.0f || yr < 0.0f || yr > 511.0f) valid = false;
        else { cx = (int)xr; cy = (int)yr; }
    }
    map[p] = valid ? (cy * 512 + cx) : -1;
}

// Label gather + all 6 fused img stages, one block per (plane, 32x32 tile).
__global__ __launch_bounds__(NT, 8) void fused_all(
    const float* __restrict__ img, const float* __restrict__ lab,
    const int* __restrict__ map, float* __restrict__ oimg,
    float* __restrict__ olab)
{
    __shared__ float bufA[BUFA_SZ];
    __shared__ float bufB[BUFB_SZ];
    int tid = threadIdx.x;
    int b = blockIdx.x;
    int plane = b >> 8, tile = b & 255;
    int tx0 = (tile & 15) * TS, ty0 = (tile >> 4) * TS;
    const float* gin = img + plane * HW;
    const float* lin = lab + plane * HW;
    float* go = oimg + plane * HW;
    float* lo = olab + plane * HW;

    // ---- label tile (independent; overlaps img work) ----
    #pragma unroll
    for (int k = 0; k < (TS * TS) / NT; ++k) {
        int ii = tid + k * NT;
        int p = (ty0 + (ii >> 5)) * 512 + tx0 + (ii & 31);
        int m = map[p];
        float v = (m >= 0) ? lin[m] : 0.f;
        __builtin_nontemporal_store(v, &lo[p]);
    }

    // ---- region chain (uniform across threads) ----
    Box R6 = {tx0, tx0 + TS - 1, ty0, ty0 + TS - 1};
    Box R5 = back_box(R6, 1.0f, 0.05f, -12.775f, -0.03f, 1.0f, 7.665f);   // shear
    R5.x1 = min(R5.x1, R5.x0 + W5 - 1); R5.y1 = min(R5.y1, R5.y0 + H5 - 1);
    Box R4 = back_box(R5, CR, -SR, K5CX, SR, CR, K5CY);                   // rotate
    R4.x1 = min(R4.x1, R4.x0 + W4 - 1); R4.y1 = min(R4.y1, R4.y0 + H4 - 1);
    Box R3 = back_box(R4, 0.9f, 0.0f, 25.55f, 0.0f, 0.9f, 25.55f);        // zoom
    R3.x1 = min(R3.x1, R3.x0 + W3 - 1); R3.y1 = min(R3.y1, R3.y0 + H3 - 1);
    Box R2 = back_box(R3, 1.1f, 0.0f, -25.55f, 0.0f, 0.95f, 12.775f);     // scale

    bool dead = (R2.x1 < 0 || R2.x0 > 511 || R2.y1 < 0 || R2.y0 > 511)
             || (R3.x1 < 0 || R3.x0 > 511 || R3.y1 < 0 || R3.y0 > 511)
             || (R4.x1 < 0 || R4.x0 > 511 || R4.y1 < 0 || R4.y0 > 511)
             || (R5.x1 < 0 || R5.x0 > 511 || R5.y1 < 0 || R5.y0 > 511);
    if (dead) {
        #pragma unroll
        for (int k = 0; k < (TS * TS) / NT; ++k) {
            int ii = tid + k * NT;
            __builtin_nontemporal_store(0.f,
                &go[(ty0 + (ii >> 5)) * 512 + tx0 + (ii & 31)]);
        }
        return;
    }

    // interior: every PADDED region cell has fully-valid taps & coords
    bool interior =
        R2.x0 >= 0 && R2.x0 + W2 - 1 <= 495 && R2.y0 >= 11 && R2.y0 + H2 - 1 <= 511 &&
        R3.x0 >= 0 && R3.x0 + W3 - 1 <= 511 && R3.y0 >= 0 && R3.y0 + H3 - 1 <= 511 &&
        R4.x0 >= 0 && R4.x0 + W4 - 1 <= 511 && R4.y0 >= 0 && R4.y0 + H4 - 1 <= 511 &&
        R5.x0 >= 0 && R5.x0 + W5 - 1 <= 511 && R5.y0 >= 0 && R5.y0 + H5 - 1 <= 511;

    if (interior)
        img_tile<true >(tid, gin, go, tx0, ty0, R2, R3, R4, R5, bufA, bufB);
    else
        img_tile<false>(tid, gin, go, tx0, ty0, R2, R3, R4, R5, bufA, bufB);
}

extern "C" void kernel_launch(void* const* d_in, const int* in_sizes, int n_in,
                              void* d_out, int out_size, void* d_ws, size_t ws_size,
                              hipStream_t stream) {
    const float* img_in = (const float*)d_in[0];
    const float* lab_in = (const float*)d_in[1];
    float* out_img = (float*)d_out;
    float* out_lab = (float*)d_out + TOTAL;
    int* map = (int*)d_ws;

    compose_nearest_map<<<(HW + 255) / 256, 256, 0, stream>>>(map);
    fused_all<<<48 * 256, NT, 0, stream>>>(img_in, lab_in, map, out_img, out_lab);
}

// Round 6
// 78.121 us; speedup vs baseline: 3.5248x; 1.1474x over previous
//
#include <hip/hip_runtime.h>
#include <math.h>

#define HW 262144            // 512*512
#define TOTAL 12582912       // 48 planes * HW
#define TS 32
#define NT 512               // threads per block
#define P 3                  // planes per block (all planes share the transform)
#define NGROUP 16            // 48 / P

#define CR 0.8910065241883679f   // cos(27 deg)
#define SR 0.45399049973954675f  // sin(27 deg)

#define K5CX (255.5f * (1.0f - CR + SR))
#define K5CY (255.5f * (1.0f - SR - CR))

// Fixed padded region dims (>= max true span at any tile position)
#define W2 52
#define H2 44
#define W3 46
#define H3 45
#define W4 49
#define H4 48
#define W5 36
#define H5 35
#define BUFA_SZ 2352   // max(W2*H2=2288, W4*H4=2352)  per plane
#define BUFB_SZ 2070   // max(W3*H3=2070, W5*H5=1260)  per plane

struct Box { int x0, x1, y0, y1; };

__device__ __forceinline__ Box back_box(Box d, float A, float B, float C,
                                        float D, float E, float F) {
    float xa = (float)d.x0, xb = (float)d.x1, ya = (float)d.y0, yb = (float)d.y1;
    float mnx = fminf(A * xa, A * xb) + fminf(B * ya, B * yb) + C;
    float mxx = fmaxf(A * xa, A * xb) + fmaxf(B * ya, B * yb) + C;
    float mny = fminf(D * xa, D * xb) + fminf(E * ya, E * yb) + F;
    float mxy = fmaxf(D * xa, D * xb) + fmaxf(E * ya, E * yb) + F;
    Box s;
    s.x0 = (int)floorf(mnx); s.x1 = (int)floorf(mxx) + 1;
    s.y0 = (int)floorf(mny); s.y1 = (int)floorf(mxy) + 1;
    return s;
}

// ---- stage 2 (translate, mirror folded): global -> bufA, P planes ----
// Constant weights wx=0.36, wy=0.76; taps at x = 496-pxi, 495-pxi; rows pyi-11, pyi-10.
template <bool INT>
__device__ __forceinline__ void s2_eval(int i, const float* __restrict__ gin,
                                        float* __restrict__ dst, int rx0, int ry0)
{
    int ly = i / W2;
    int lx = i - ly * W2;
    int pxi = rx0 + lx, pyi = ry0 + ly;
    if (INT) {
        int off = ((pyi - 11) << 9) + (496 - pxi);
        #pragma unroll
        for (int p = 0; p < P; ++p) {
            const float* g0 = gin + p * HW + off;
            float v00 = g0[0], v01 = g0[-1];
            float v10 = g0[512], v11 = g0[511];
            float h0 = fmaf(0.36f, v01, 0.64f * v00);
            float h1 = fmaf(0.36f, v11, 0.64f * v10);
            dst[p * BUFA_SZ + i] = fmaf(0.76f, h1, 0.24f * h0);
        }
    } else {
        float wx0m = ((unsigned)pxi <= 496u) ? 0.64f : 0.0f;
        float wx1m = ((unsigned)pxi <= 495u) ? 0.36f : 0.0f;
        float wy0m = ((unsigned)(pyi - 11) <= 500u) ? 0.24f : 0.0f;
        float wy1m = ((unsigned)(pyi - 10) <= 501u) ? 0.76f : 0.0f;
        int xc0 = min(max(496 - pxi, 0), 511);
        int xc1 = min(max(495 - pxi, 0), 511);
        int r0 = min(max(pyi - 11, 0), 511) << 9;
        int r1 = min(max(pyi - 10, 0), 511) << 9;
        #pragma unroll
        for (int p = 0; p < P; ++p) {
            const float* g = gin + p * HW;
            float v00 = g[r0 + xc0], v01 = g[r0 + xc1];
            float v10 = g[r1 + xc0], v11 = g[r1 + xc1];
            float h0 = fmaf(wx1m, v01, wx0m * v00);
            float h1 = fmaf(wx1m, v11, wx0m * v10);
            dst[p * BUFA_SZ + i] = fmaf(wy1m, h1, wy0m * h0);
        }
    }
}

// ---- LDS -> LDS bilinear stage, P planes off one shared address ----
template <int SW, int SH, int DW, int SSTR, int DSTR, bool AXIS, bool INT>
__device__ __forceinline__ void lds_eval(int i, float A, float B, float Cs,
    float D, float E, float Fs, const float* __restrict__ src,
    float* __restrict__ dst, int dx0, int dy0)
{
    int ly = i / DW;
    int lx = i - ly * DW;
    int pxi = dx0 + lx, pyi = dy0 + ly;
    float px = (float)pxi, py = (float)pyi;
    float fx = AXIS ? fmaf(A, px, Cs) : fmaf(A, px, fmaf(B, py, Cs));
    float fy = AXIS ? fmaf(E, py, Fs) : fmaf(D, px, fmaf(E, py, Fs));
    float xf = floorf(fx), yf = floorf(fy);
    float wx = fx - xf, wy = fy - yf;
    int x0 = (int)xf, y0 = (int)yf;
    if (!INT) { x0 = min(max(x0, 0), SW - 2); y0 = min(max(y0, 0), SH - 2); }
    int sbase = y0 * SW + x0;
    bool oob = ((unsigned)pxi >= 512u || (unsigned)pyi >= 512u);
    #pragma unroll
    for (int p = 0; p < P; ++p) {
        const float* s = src + p * SSTR + sbase;   // p*SSTR folds into DS imm offset
        float v00 = s[0], v01 = s[1];
        float v10 = s[SW], v11 = s[SW + 1];
        float a0 = fmaf(wx, v01 - v00, v00);
        float a1 = fmaf(wx, v11 - v10, v10);
        float val = fmaf(wy, a1 - a0, a0);
        if (!INT) { if (oob) val = 0.f; }
        dst[p * DSTR + i] = val;
    }
}

template <int SW, int SH, int DW, int DTOT, int SSTR, int DSTR, bool AXIS, bool INT>
__device__ __forceinline__ void stage_lds(int tid, float A, float B, float Cs,
    float D, float E, float Fs, const float* __restrict__ src,
    float* __restrict__ dst, int dx0, int dy0)
{
    constexpr int FULL = DTOT / NT;
    constexpr int TAIL = DTOT - FULL * NT;
    #pragma unroll
    for (int k = 0; k < FULL; ++k)
        lds_eval<SW, SH, DW, SSTR, DSTR, AXIS, INT>(tid + k * NT, A, B, Cs,
                                                    D, E, Fs, src, dst, dx0, dy0);
    if (TAIL && tid < TAIL)
        lds_eval<SW, SH, DW, SSTR, DSTR, AXIS, INT>(tid + FULL * NT, A, B, Cs,
                                                    D, E, Fs, src, dst, dx0, dy0);
}

// ---- stage 6 (shear): bufB(R5) -> global, P planes ----
template <bool INT>
__device__ __forceinline__ void s6_eval(int ii, const float* __restrict__ src,
    float* __restrict__ go, int tx0, int ty0, int sx0, int sy0)
{
    int lx = ii & 31, ly = ii >> 5;
    float px = (float)(tx0 + lx), py = (float)(ty0 + ly);
    float fx = fmaf(0.05f, py, -12.775f - (float)sx0) + px;
    float fy = fmaf(-0.03f, px, 7.665f - (float)sy0) + py;
    float xf = floorf(fx), yf = floorf(fy);
    float wx = fx - xf, wy = fy - yf;
    int x0 = (int)xf, y0 = (int)yf;
    if (!INT) { x0 = min(max(x0, 0), W5 - 2); y0 = min(max(y0, 0), H5 - 2); }
    int sbase = y0 * W5 + x0;
    int gidx = (ty0 + ly) * 512 + tx0 + lx;
    #pragma unroll
    for (int p = 0; p < P; ++p) {
        const float* s = src + p * BUFB_SZ + sbase;
        float v00 = s[0], v01 = s[1];
        float v10 = s[W5], v11 = s[W5 + 1];
        float a0 = fmaf(wx, v01 - v00, v00);
        float a1 = fmaf(wx, v11 - v10, v10);
        float val = fmaf(wy, a1 - a0, a0);
        __builtin_nontemporal_store(val, &go[p * HW + gidx]);
    }
}

// ---- full img tile pipeline for P planes ----
template <bool INT>
__device__ __forceinline__ void img_tile(int tid, const float* __restrict__ gin,
    float* __restrict__ go, int tx0, int ty0,
    Box R2, Box R3, Box R4, Box R5, float* bufA, float* bufB)
{
    // stage 2: global -> bufA(R2)
    {
        constexpr int FULL = (W2 * H2) / NT;
        constexpr int TAIL = W2 * H2 - FULL * NT;
        #pragma unroll
        for (int k = 0; k < FULL; ++k)
            s2_eval<INT>(tid + k * NT, gin, bufA, R2.x0, R2.y0);
        if (tid < TAIL) s2_eval<INT>(tid + FULL * NT, gin, bufA, R2.x0, R2.y0);
    }
    __syncthreads();
    // stage 3 (scale): bufA(R2) -> bufB(R3)
    stage_lds<W2, H2, W3, W3 * H3, BUFA_SZ, BUFB_SZ, true, INT>(tid,
        1.1f, 0.0f, -25.55f - (float)R2.x0,
        0.0f, 0.95f, 12.775f - (float)R2.y0, bufA, bufB, R3.x0, R3.y0);
    __syncthreads();
    // stage 4 (zoom): bufB(R3) -> bufA(R4)
    stage_lds<W3, H3, W4, W4 * H4, BUFB_SZ, BUFA_SZ, true, INT>(tid,
        0.9f, 0.0f, 25.55f - (float)R3.x0,
        0.0f, 0.9f, 25.55f - (float)R3.y0, bufB, bufA, R4.x0, R4.y0);
    __syncthreads();
    // stage 5 (rotate): bufA(R4) -> bufB(R5)
    stage_lds<W4, H4, W5, W5 * H5, BUFA_SZ, BUFB_SZ, false, INT>(tid,
        CR, -SR, K5CX - (float)R4.x0,
        SR,  CR, K5CY - (float)R4.y0, bufA, bufB, R5.x0, R5.y0);
    __syncthreads();
    // stage 6 (shear): bufB(R5) -> global tiles
    {
        constexpr int FULL = (TS * TS) / NT;
        #pragma unroll
        for (int k = 0; k < FULL; ++k)
            s6_eval<INT>(tid + k * NT, bufB, go, tx0, ty0, R5.x0, R5.y0);
    }
}

// Compose the 6 nearest-neighbor integer maps (exact vs sequential resampling).
__global__ void compose_nearest_map(int* __restrict__ map) {
    int p = blockIdx.x * blockDim.x + threadIdx.x;
    if (p >= HW) return;
    const float TH[6][6] = {
        { 1.0f,  0.05f, 0.0f,  -0.03f, 1.0f,  0.0f },   // shear
        { CR,    -SR,   0.0f,   SR,    CR,    0.0f },   // rotate
        { 0.9f,  0.0f,  0.0f,   0.0f,  0.9f,  0.0f },   // zoom
        { 1.1f,  0.0f,  0.0f,   0.0f,  0.95f, 0.0f },   // scale
        { 1.0f,  0.0f,  0.06f,  0.0f,  1.0f, -0.04f },  // translate
        { -1.0f, 0.0f,  0.0f,   0.0f,  1.0f,  0.0f },   // mirror
    };
    int cx = p & 511, cy = p >> 9;
    bool valid = true;
    #pragma unroll
    for (int s = 0; s < 6; ++s) {
        if (!valid) break;
        float x = (cx + 0.5f) * (2.0f / 512.0f) - 1.0f;
        float y = (cy + 0.5f) * (2.0f / 512.0f) - 1.0f;
        float gx = TH[s][0] * x + TH[s][1] * y + TH[s][2];
        float gy = TH[s][3] * x + TH[s][4] * y + TH[s][5];
        float ix = ((gx + 1.0f) * 512.0f - 1.0f) * 0.5f;
        float iy = ((gy + 1.0f) * 512.0f - 1.0f) * 0.5f;
        float xr = rintf(ix), yr = rintf(iy);
        if (xr < 0.0f || xr > 511.0f || yr < 0.0f || yr > 511.0f) valid = false;
        else { cx = (int)xr; cy = (int)yr; }
    }
    map[p] = valid ? (cy * 512 + cx) : -1;
}

// One block per (plane-group, 32x32 tile): label gather + 6 fused img stages
// for P planes sharing all coordinate math.
__global__ __launch_bounds__(NT, 6) void fused_all(
    const float* __restrict__ img, const float* __restrict__ lab,
    const int* __restrict__ map, float* __restrict__ oimg,
    float* __restrict__ olab)
{
    __shared__ float bufA[P * BUFA_SZ];
    __shared__ float bufB[P * BUFB_SZ];
    int tid = threadIdx.x;
    int b = blockIdx.x;
    int group = b >> 8, tile = b & 255;
    int tx0 = (tile & 15) * TS, ty0 = (tile >> 4) * TS;
    int pbase = group * P;
    const float* gin = img + pbase * HW;
    const float* lin = lab + pbase * HW;
    float* go = oimg + pbase * HW;
    float* lo = olab + pbase * HW;

    // ---- label tiles: one map read feeds P planes ----
    {
        constexpr int FULL = (TS * TS) / NT;
        #pragma unroll
        for (int k = 0; k < FULL; ++k) {
            int ii = tid + k * NT;
            int gidx = (ty0 + (ii >> 5)) * 512 + tx0 + (ii & 31);
            int m = map[gidx];
            #pragma unroll
            for (int p = 0; p < P; ++p) {
                float v = (m >= 0) ? lin[p * HW + m] : 0.f;
                __builtin_nontemporal_store(v, &lo[p * HW + gidx]);
            }
        }
    }

    // ---- region chain (uniform across threads) ----
    Box R6 = {tx0, tx0 + TS - 1, ty0, ty0 + TS - 1};
    Box R5 = back_box(R6, 1.0f, 0.05f, -12.775f, -0.03f, 1.0f, 7.665f);   // shear
    R5.x1 = min(R5.x1, R5.x0 + W5 - 1); R5.y1 = min(R5.y1, R5.y0 + H5 - 1);
    Box R4 = back_box(R5, CR, -SR, K5CX, SR, CR, K5CY);                   // rotate
    R4.x1 = min(R4.x1, R4.x0 + W4 - 1); R4.y1 = min(R4.y1, R4.y0 + H4 - 1);
    Box R3 = back_box(R4, 0.9f, 0.0f, 25.55f, 0.0f, 0.9f, 25.55f);        // zoom
    R3.x1 = min(R3.x1, R3.x0 + W3 - 1); R3.y1 = min(R3.y1, R3.y0 + H3 - 1);
    Box R2 = back_box(R3, 1.1f, 0.0f, -25.55f, 0.0f, 0.95f, 12.775f);     // scale

    bool dead = (R2.x1 < 0 || R2.x0 > 511 || R2.y1 < 0 || R2.y0 > 511)
             || (R3.x1 < 0 || R3.x0 > 511 || R3.y1 < 0 || R3.y0 > 511)
             || (R4.x1 < 0 || R4.x0 > 511 || R4.y1 < 0 || R4.y0 > 511)
             || (R5.x1 < 0 || R5.x0 > 511 || R5.y1 < 0 || R5.y0 > 511);
    if (dead) {
        constexpr int FULL = (TS * TS) / NT;
        #pragma unroll
        for (int k = 0; k < FULL; ++k) {
            int ii = tid + k * NT;
            int gidx = (ty0 + (ii >> 5)) * 512 + tx0 + (ii & 31);
            #pragma unroll
            for (int p = 0; p < P; ++p)
                __builtin_nontemporal_store(0.f, &go[p * HW + gidx]);
        }
        return;
    }

    // interior: every PADDED region cell has fully-valid taps & coords
    bool interior =
        R2.x0 >= 0 && R2.x0 + W2 - 1 <= 495 && R2.y0 >= 11 && R2.y0 + H2 - 1 <= 511 &&
        R3.x0 >= 0 && R3.x0 + W3 - 1 <= 511 && R3.y0 >= 0 && R3.y0 + H3 - 1 <= 511 &&
        R4.x0 >= 0 && R4.x0 + W4 - 1 <= 511 && R4.y0 >= 0 && R4.y0 + H4 - 1 <= 511 &&
        R5.x0 >= 0 && R5.x0 + W5 - 1 <= 511 && R5.y0 >= 0 && R5.y0 + H5 - 1 <= 511;

    if (interior)
        img_tile<true >(tid, gin, go, tx0, ty0, R2, R3, R4, R5, bufA, bufB);
    else
        img_tile<false>(tid, gin, go, tx0, ty0, R2, R3, R4, R5, bufA, bufB);
}

extern "C" void kernel_launch(void* const* d_in, const int* in_sizes, int n_in,
                              void* d_out, int out_size, void* d_ws, size_t ws_size,
                              hipStream_t stream) {
    const float* img_in = (const float*)d_in[0];
    const float* lab_in = (const float*)d_in[1];
    float* out_img = (float*)d_out;
    float* out_lab = (float*)d_out + TOTAL;
    int* map = (int*)d_ws;

    compose_nearest_map<<<(HW + 255) / 256, 256, 0, stream>>>(map);
    fused_all<<<NGROUP * 256, NT, 0, stream>>>(img_in, lab_in, map, out_img, out_lab);
}

// Round 7
// 67.864 us; speedup vs baseline: 4.0575x; 1.1511x over previous
//
#include <hip/hip_runtime.h>
#include <math.h>

#define HW 262144            // 512*512
#define TOTAL 12582912       // 48 planes * HW
#define TS 32
#define NT 512               // threads per block
#define P 2                  // planes per block, element-interleaved as float2
#define NGROUP 24            // 48 / P

#define CR 0.8910065241883679f   // cos(27 deg)
#define SR 0.45399049973954675f  // sin(27 deg)

#define K5CX (255.5f * (1.0f - CR + SR))
#define K5CY (255.5f * (1.0f - SR - CR))

// Fixed padded region dims (>= max true span at any tile position)
#define W2 52
#define H2 44
#define W3 46
#define H3 45
#define W4 49
#define H4 48
#define W5 36
#define H5 35
#define BUFA_SZ 2352   // float2 cells: max(W2*H2=2288, W4*H4=2352)
#define BUFB_SZ 2070   // float2 cells: max(W3*H3=2070, W5*H5=1260)

struct Box { int x0, x1, y0, y1; };

__device__ __forceinline__ Box back_box(Box d, float A, float B, float C,
                                        float D, float E, float F) {
    float xa = (float)d.x0, xb = (float)d.x1, ya = (float)d.y0, yb = (float)d.y1;
    float mnx = fminf(A * xa, A * xb) + fminf(B * ya, B * yb) + C;
    float mxx = fmaxf(A * xa, A * xb) + fmaxf(B * ya, B * yb) + C;
    float mny = fminf(D * xa, D * xb) + fminf(E * ya, E * yb) + F;
    float mxy = fmaxf(D * xa, D * xb) + fmaxf(E * ya, E * yb) + F;
    Box s;
    s.x0 = (int)floorf(mnx); s.x1 = (int)floorf(mxx) + 1;
    s.y0 = (int)floorf(mny); s.y1 = (int)floorf(mxy) + 1;
    return s;
}

__device__ __forceinline__ float2 lerp2(float w, float2 a, float2 b) {
    // a + w*(b-a), component-wise (compiler may pack to v_pk_fma_f32)
    float2 r;
    r.x = fmaf(w, b.x - a.x, a.x);
    r.y = fmaf(w, b.y - a.y, a.y);
    return r;
}

// ---- stage 2 (translate, mirror folded): global -> bufA (float2), 2 planes ----
// Constant weights wx=0.36, wy=0.76; taps at x = 496-pxi, 495-pxi; rows pyi-11, pyi-10.
template <bool INT>
__device__ __forceinline__ void s2_eval(int i, const float* __restrict__ gin,
                                        float2* __restrict__ dst, int rx0, int ry0)
{
    int ly = i / W2;
    int lx = i - ly * W2;
    int pxi = rx0 + lx, pyi = ry0 + ly;
    if (INT) {
        int off = ((pyi - 11) << 9) + (496 - pxi);
        float2 o;
        {
            const float* g0 = gin + off;
            float h0 = fmaf(0.36f, g0[-1], 0.64f * g0[0]);
            float h1 = fmaf(0.36f, g0[511], 0.64f * g0[512]);
            o.x = fmaf(0.76f, h1, 0.24f * h0);
        }
        {
            const float* g1 = gin + HW + off;
            float h0 = fmaf(0.36f, g1[-1], 0.64f * g1[0]);
            float h1 = fmaf(0.36f, g1[511], 0.64f * g1[512]);
            o.y = fmaf(0.76f, h1, 0.24f * h0);
        }
        dst[i] = o;
    } else {
        float wx0m = ((unsigned)pxi <= 496u) ? 0.64f : 0.0f;
        float wx1m = ((unsigned)pxi <= 495u) ? 0.36f : 0.0f;
        float wy0m = ((unsigned)(pyi - 11) <= 500u) ? 0.24f : 0.0f;
        float wy1m = ((unsigned)(pyi - 10) <= 501u) ? 0.76f : 0.0f;
        int xc0 = min(max(496 - pxi, 0), 511);
        int xc1 = min(max(495 - pxi, 0), 511);
        int r0 = min(max(pyi - 11, 0), 511) << 9;
        int r1 = min(max(pyi - 10, 0), 511) << 9;
        float2 o;
        #pragma unroll
        for (int p = 0; p < P; ++p) {
            const float* g = gin + p * HW;
            float v00 = g[r0 + xc0], v01 = g[r0 + xc1];
            float v10 = g[r1 + xc0], v11 = g[r1 + xc1];
            float h0 = fmaf(wx1m, v01, wx0m * v00);
            float h1 = fmaf(wx1m, v11, wx0m * v10);
            float val = fmaf(wy1m, h1, wy0m * h0);
            if (p == 0) o.x = val; else o.y = val;
        }
        dst[i] = o;
    }
}

// ---- LDS -> LDS bilinear stage, both planes per float2 cell ----
template <int SW, int SH, int DW, bool AXIS, bool INT>
__device__ __forceinline__ void lds_eval(int i, float A, float B, float Cs,
    float D, float E, float Fs, const float2* __restrict__ src,
    float2* __restrict__ dst, int dx0, int dy0)
{
    int ly = i / DW;
    int lx = i - ly * DW;
    int pxi = dx0 + lx, pyi = dy0 + ly;
    float px = (float)pxi, py = (float)pyi;
    float fx = AXIS ? fmaf(A, px, Cs) : fmaf(A, px, fmaf(B, py, Cs));
    float fy = AXIS ? fmaf(E, py, Fs) : fmaf(D, px, fmaf(E, py, Fs));
    float xf = floorf(fx), yf = floorf(fy);
    float wx = fx - xf, wy = fy - yf;
    int x0 = (int)xf, y0 = (int)yf;
    if (!INT) { x0 = min(max(x0, 0), SW - 2); y0 = min(max(y0, 0), SH - 2); }
    const float2* s = src + y0 * SW + x0;
    float2 v00 = s[0], v01 = s[1];        // ds_read2_b64 pair
    float2 v10 = s[SW], v11 = s[SW + 1];
    float2 a0 = lerp2(wx, v00, v01);
    float2 a1 = lerp2(wx, v10, v11);
    float2 val = lerp2(wy, a0, a1);
    if (!INT) {
        if ((unsigned)pxi >= 512u || (unsigned)pyi >= 512u) { val.x = 0.f; val.y = 0.f; }
    }
    dst[i] = val;                          // ds_write_b64
}

template <int SW, int SH, int DW, int DTOT, bool AXIS, bool INT>
__device__ __forceinline__ void stage_lds(int tid, float A, float B, float Cs,
    float D, float E, float Fs, const float2* __restrict__ src,
    float2* __restrict__ dst, int dx0, int dy0)
{
    constexpr int FULL = DTOT / NT;
    constexpr int TAIL = DTOT - FULL * NT;
    #pragma unroll
    for (int k = 0; k < FULL; ++k)
        lds_eval<SW, SH, DW, AXIS, INT>(tid + k * NT, A, B, Cs, D, E, Fs,
                                        src, dst, dx0, dy0);
    if (TAIL && tid < TAIL)
        lds_eval<SW, SH, DW, AXIS, INT>(tid + FULL * NT, A, B, Cs, D, E, Fs,
                                        src, dst, dx0, dy0);
}

// ---- stage 6 (shear): bufB(R5, float2) -> global, 2 planes ----
template <bool INT>
__device__ __forceinline__ void s6_eval(int ii, const float2* __restrict__ src,
    float* __restrict__ go, int tx0, int ty0, int sx0, int sy0)
{
    int lx = ii & 31, ly = ii >> 5;
    float px = (float)(tx0 + lx), py = (float)(ty0 + ly);
    float fx = fmaf(0.05f, py, -12.775f - (float)sx0) + px;
    float fy = fmaf(-0.03f, px, 7.665f - (float)sy0) + py;
    float xf = floorf(fx), yf = floorf(fy);
    float wx = fx - xf, wy = fy - yf;
    int x0 = (int)xf, y0 = (int)yf;
    if (!INT) { x0 = min(max(x0, 0), W5 - 2); y0 = min(max(y0, 0), H5 - 2); }
    const float2* s = src + y0 * W5 + x0;
    float2 v00 = s[0], v01 = s[1];
    float2 v10 = s[W5], v11 = s[W5 + 1];
    float2 a0 = lerp2(wx, v00, v01);
    float2 a1 = lerp2(wx, v10, v11);
    float2 val = lerp2(wy, a0, a1);
    int gidx = (ty0 + ly) * 512 + tx0 + lx;
    __builtin_nontemporal_store(val.x, &go[gidx]);
    __builtin_nontemporal_store(val.y, &go[HW + gidx]);
}

// ---- full img tile pipeline for 2 interleaved planes ----
template <bool INT>
__device__ __forceinline__ void img_tile(int tid, const float* __restrict__ gin,
    float* __restrict__ go, int tx0, int ty0,
    Box R2, Box R3, Box R4, Box R5, float2* bufA, float2* bufB)
{
    // stage 2: global -> bufA(R2)
    {
        constexpr int FULL = (W2 * H2) / NT;
        constexpr int TAIL = W2 * H2 - FULL * NT;
        #pragma unroll
        for (int k = 0; k < FULL; ++k)
            s2_eval<INT>(tid + k * NT, gin, bufA, R2.x0, R2.y0);
        if (tid < TAIL) s2_eval<INT>(tid + FULL * NT, gin, bufA, R2.x0, R2.y0);
    }
    __syncthreads();
    // stage 3 (scale): bufA(R2) -> bufB(R3)
    stage_lds<W2, H2, W3, W3 * H3, true, INT>(tid,
        1.1f, 0.0f, -25.55f - (float)R2.x0,
        0.0f, 0.95f, 12.775f - (float)R2.y0, bufA, bufB, R3.x0, R3.y0);
    __syncthreads();
    // stage 4 (zoom): bufB(R3) -> bufA(R4)
    stage_lds<W3, H3, W4, W4 * H4, true, INT>(tid,
        0.9f, 0.0f, 25.55f - (float)R3.x0,
        0.0f, 0.9f, 25.55f - (float)R3.y0, bufB, bufA, R4.x0, R4.y0);
    __syncthreads();
    // stage 5 (rotate): bufA(R4) -> bufB(R5)
    stage_lds<W4, H4, W5, W5 * H5, false, INT>(tid,
        CR, -SR, K5CX - (float)R4.x0,
        SR,  CR, K5CY - (float)R4.y0, bufA, bufB, R5.x0, R5.y0);
    __syncthreads();
    // stage 6 (shear): bufB(R5) -> global tiles
    {
        constexpr int FULL = (TS * TS) / NT;
        #pragma unroll
        for (int k = 0; k < FULL; ++k)
            s6_eval<INT>(tid + k * NT, bufB, go, tx0, ty0, R5.x0, R5.y0);
    }
}

// Compose the 6 nearest-neighbor integer maps (exact vs sequential resampling).
__global__ void compose_nearest_map(int* __restrict__ map) {
    int p = blockIdx.x * blockDim.x + threadIdx.x;
    if (p >= HW) return;
    const float TH[6][6] = {
        { 1.0f,  0.05f, 0.0f,  -0.03f, 1.0f,  0.0f },   // shear
        { CR,    -SR,   0.0f,   SR,    CR,    0.0f },   // rotate
        { 0.9f,  0.0f,  0.0f,   0.0f,  0.9f,  0.0f },   // zoom
        { 1.1f,  0.0f,  0.0f,   0.0f,  0.95f, 0.0f },   // scale
        { 1.0f,  0.0f,  0.06f,  0.0f,  1.0f, -0.04f },  // translate
        { -1.0f, 0.0f,  0.0f,   0.0f,  1.0f,  0.0f },   // mirror
    };
    int cx = p & 511, cy = p >> 9;
    bool valid = true;
    #pragma unroll
    for (int s = 0; s < 6; ++s) {
        if (!valid) break;
        float x = (cx + 0.5f) * (2.0f / 512.0f) - 1.0f;
        float y = (cy + 0.5f) * (2.0f / 512.0f) - 1.0f;
        float gx = TH[s][0] * x + TH[s][1] * y + TH[s][2];
        float gy = TH[s][3] * x + TH[s][4] * y + TH[s][5];
        float ix = ((gx + 1.0f) * 512.0f - 1.0f) * 0.5f;
        float iy = ((gy + 1.0f) * 512.0f - 1.0f) * 0.5f;
        float xr = rintf(ix), yr = rintf(iy);
        if (xr < 0.0f || xr > 511.0f || yr < 0.0f || yr > 511.0f) valid = false;
        else { cx = (int)xr; cy = (int)yr; }
    }
    map[p] = valid ? (cy * 512 + cx) : -1;
}

// One block per (plane-pair, 32x32 tile): label gather + 6 fused img stages
// for 2 planes sharing all coordinate math, interleaved as float2 in LDS.
__global__ __launch_bounds__(NT, 8) void fused_all(
    const float* __restrict__ img, const float* __restrict__ lab,
    const int* __restrict__ map, float* __restrict__ oimg,
    float* __restrict__ olab)
{
    __shared__ float2 bufA[BUFA_SZ];
    __shared__ float2 bufB[BUFB_SZ];
    int tid = threadIdx.x;
    int b = blockIdx.x;
    int group = b >> 8, tile = b & 255;
    int tx0 = (tile & 15) * TS, ty0 = (tile >> 4) * TS;
    int pbase = group * P;
    const float* gin = img + pbase * HW;
    const float* lin = lab + pbase * HW;
    float* go = oimg + pbase * HW;
    float* lo = olab + pbase * HW;

    // ---- label tiles: one map read feeds both planes ----
    {
        constexpr int FULL = (TS * TS) / NT;
        #pragma unroll
        for (int k = 0; k < FULL; ++k) {
            int ii = tid + k * NT;
            int gidx = (ty0 + (ii >> 5)) * 512 + tx0 + (ii & 31);
            int m = map[gidx];
            float v0 = (m >= 0) ? lin[m] : 0.f;
            float v1 = (m >= 0) ? lin[HW + m] : 0.f;
            __builtin_nontemporal_store(v0, &lo[gidx]);
            __builtin_nontemporal_store(v1, &lo[HW + gidx]);
        }
    }

    // ---- region chain (uniform across threads) ----
    Box R6 = {tx0, tx0 + TS - 1, ty0, ty0 + TS - 1};
    Box R5 = back_box(R6, 1.0f, 0.05f, -12.775f, -0.03f, 1.0f, 7.665f);   // shear
    R5.x1 = min(R5.x1, R5.x0 + W5 - 1); R5.y1 = min(R5.y1, R5.y0 + H5 - 1);
    Box R4 = back_box(R5, CR, -SR, K5CX, SR, CR, K5CY);                   // rotate
    R4.x1 = min(R4.x1, R4.x0 + W4 - 1); R4.y1 = min(R4.y1, R4.y0 + H4 - 1);
    Box R3 = back_box(R4, 0.9f, 0.0f, 25.55f, 0.0f, 0.9f, 25.55f);        // zoom
    R3.x1 = min(R3.x1, R3.x0 + W3 - 1); R3.y1 = min(R3.y1, R3.y0 + H3 - 1);
    Box R2 = back_box(R3, 1.1f, 0.0f, -25.55f, 0.0f, 0.95f, 12.775f);     // scale

    bool dead = (R2.x1 < 0 || R2.x0 > 511 || R2.y1 < 0 || R2.y0 > 511)
             || (R3.x1 < 0 || R3.x0 > 511 || R3.y1 < 0 || R3.y0 > 511)
             || (R4.x1 < 0 || R4.x0 > 511 || R4.y1 < 0 || R4.y0 > 511)
             || (R5.x1 < 0 || R5.x0 > 511 || R5.y1 < 0 || R5.y0 > 511);
    if (dead) {
        constexpr int FULL = (TS * TS) / NT;
        #pragma unroll
        for (int k = 0; k < FULL; ++k) {
            int ii = tid + k * NT;
            int gidx = (ty0 + (ii >> 5)) * 512 + tx0 + (ii & 31);
            __builtin_nontemporal_store(0.f, &go[gidx]);
            __builtin_nontemporal_store(0.f, &go[HW + gidx]);
        }
        return;
    }

    // interior: every PADDED region cell has fully-valid taps & coords
    bool interior =
        R2.x0 >= 0 && R2.x0 + W2 - 1 <= 495 && R2.y0 >= 11 && R2.y0 + H2 - 1 <= 511 &&
        R3.x0 >= 0 && R3.x0 + W3 - 1 <= 511 && R3.y0 >= 0 && R3.y0 + H3 - 1 <= 511 &&
        R4.x0 >= 0 && R4.x0 + W4 - 1 <= 511 && R4.y0 >= 0 && R4.y0 + H4 - 1 <= 511 &&
        R5.x0 >= 0 && R5.x0 + W5 - 1 <= 511 && R5.y0 >= 0 && R5.y0 + H5 - 1 <= 511;

    if (interior)
        img_tile<true >(tid, gin, go, tx0, ty0, R2, R3, R4, R5, bufA, bufB);
    else
        img_tile<false>(tid, gin, go, tx0, ty0, R2, R3, R4, R5, bufA, bufB);
}

extern "C" void kernel_launch(void* const* d_in, const int* in_sizes, int n_in,
                              void* d_out, int out_size, void* d_ws, size_t ws_size,
                              hipStream_t stream) {
    const float* img_in = (const float*)d_in[0];
    const float* lab_in = (const float*)d_in[1];
    float* out_img = (float*)d_out;
    float* out_lab = (float*)d_out + TOTAL;
    int* map = (int*)d_ws;

    compose_nearest_map<<<(HW + 255) / 256, 256, 0, stream>>>(map);
    fused_all<<<NGROUP * 256, NT, 0, stream>>>(img_in, lab_in, map, out_img, out_lab);
}